// Round 3
// baseline (522.563 us; speedup 1.0000x reference)
//
#include <hip/hip_runtime.h>
#include <hip/hip_bf16.h>
#include <stdint.h>

// Problem constants (from reference): B=1, T=4096, HID=2048, NQ=16, NKV=2, D=128
#define T_SEQ 4096
#define HID   2048
#define NQH   16
#define NKVH  2
#define DH    128
#define NQKV  2560   // 2048 (q) + 256 (k) + 256 (v)
#define SCALE 0.08838834764831845f

typedef unsigned short u16;
typedef __attribute__((ext_vector_type(8))) short bf16x8;   // 8 bf16 = 4 VGPR
typedef __attribute__((ext_vector_type(4))) float f32x4;

#define MFMA(a, b, c) __builtin_amdgcn_mfma_f32_16x16x32_bf16(a, b, c, 0, 0, 0)

static __device__ __forceinline__ u16 f2bf(float f) {
    union { float f; uint32_t u; } v; v.f = f;
    uint32_t r = v.u + 0x7fffu + ((v.u >> 16) & 1u);   // RNE
    return (u16)(r >> 16);
}
static __device__ __forceinline__ float bf2f(u16 u) {
    union { uint32_t u; float f; } v; v.u = ((uint32_t)u) << 16;
    return v.f;
}

// async global->LDS, 16B per lane. LDS dest must be linear in lane order.
static __device__ __forceinline__ void gload_lds16(const void* g, void* l) {
    __builtin_amdgcn_global_load_lds((const __attribute__((address_space(1))) uint32_t*)g,
                                     (__attribute__((address_space(3))) uint32_t*)l,
                                     16, 0, 0);
}

// ---------------- fp32 -> bf16 convert, all 5 tensors in one exact-grid launch ---------
// f4-unit segment bounds: x[0,2097152) wq[..3145728) wk[..3276800) wv[..3407872) wo[..4456448)
__global__ void k_cvt_all(const float4* __restrict__ x,  const float4* __restrict__ wq,
                          const float4* __restrict__ wk, const float4* __restrict__ wv,
                          const float4* __restrict__ wo,
                          u16* __restrict__ x_bf, u16* __restrict__ wqkv_bf,
                          u16* __restrict__ wo_bf) {
    const int i = blockIdx.x * 256 + threadIdx.x;
    const float4* src; u16* dst; int off;
    if (i < 2097152)      { src = x;  dst = x_bf;              off = i; }
    else if (i < 3145728) { src = wq; dst = wqkv_bf;           off = i - 2097152; }
    else if (i < 3276800) { src = wk; dst = wqkv_bf + 4194304; off = i - 3145728; }
    else if (i < 3407872) { src = wv; dst = wqkv_bf + 4718592; off = i - 3276800; }
    else                  { src = wo; dst = wo_bf;             off = i - 3407872; }
    const float4 v = src[off];
    const uint64_t o = (uint64_t)f2bf(v.x) | ((uint64_t)f2bf(v.y) << 16) |
                       ((uint64_t)f2bf(v.z) << 32) | ((uint64_t)f2bf(v.w) << 48);
    *(uint64_t*)(dst + (size_t)off * 4) = o;
}

// ---------------- bias concat (bq|bk|bv), fp32 ----------------
__global__ void k_bias(const float* __restrict__ bq, const float* __restrict__ bk,
                       const float* __restrict__ bv, float* __restrict__ out) {
    int i = blockIdx.x * 256 + threadIdx.x;          // 0..2559
    float v = (i < 2048) ? bq[i] : (i < 2304 ? bk[i - 2048] : bv[i - 2304]);
    out[i] = v;
}

// ---------------- GEMM: C[M,N] = A[M,K] @ B[N,K]^T (+bias), m97 structure ----------
// 128x128 tile, BK=32, 4 waves (2x2), 16x16x32 MFMA, global_load_lds staging.
// LDS row stride 64B -> fragment reads are bank-minimal (8 lanes/quad). No swizzle needed.
template <int OUT_BF16>
__global__ __launch_bounds__(256, 2) void k_gemm_bt(const u16* __restrict__ A,
                                                    const u16* __restrict__ B,
                                                    const float* __restrict__ bias,
                                                    void* __restrict__ Cout,
                                                    int M, int N, int K) {
    __shared__ u16 As[128 * 32];
    __shared__ u16 Bs[128 * 32];
    const int tid  = threadIdx.x;
    const int lane = tid & 63, w = tid >> 6;
    const int wr = w >> 1, wc = w & 1;
    const int lrow = lane & 15, lgrp = lane >> 4;
    const int m0 = blockIdx.x * 128, n0 = blockIdx.y * 128;

    f32x4 acc[4][4] = {};
    const int arow = tid >> 2, acol = (tid & 3) * 8;   // staging: 64 rows/instr
    const u16* Abase = A + (size_t)(m0 + arow) * K + acol;
    const u16* Bbase = B + (size_t)(n0 + arow) * K + acol;

    for (int kk = 0; kk < K; kk += 32) {
        gload_lds16(Abase + kk,                   &As[tid * 8]);
        gload_lds16(Abase + kk + (size_t)64 * K,  &As[2048 + tid * 8]);
        gload_lds16(Bbase + kk,                   &Bs[tid * 8]);
        gload_lds16(Bbase + kk + (size_t)64 * K,  &Bs[2048 + tid * 8]);
        __syncthreads();
        bf16x8 af[4], bfv[4];
#pragma unroll
        for (int mb = 0; mb < 4; ++mb)
            af[mb] = *(const bf16x8*)&As[(wr * 64 + mb * 16 + lrow) * 32 + lgrp * 8];
#pragma unroll
        for (int nb = 0; nb < 4; ++nb)
            bfv[nb] = *(const bf16x8*)&Bs[(wc * 64 + nb * 16 + lrow) * 32 + lgrp * 8];
#pragma unroll
        for (int mb = 0; mb < 4; ++mb)
#pragma unroll
            for (int nb = 0; nb < 4; ++nb)
                acc[mb][nb] = MFMA(af[mb], bfv[nb], acc[mb][nb]);
        __syncthreads();
    }
    // epilogue: C/D layout col=lane&15, row=(lane>>4)*4+reg
#pragma unroll
    for (int mb = 0; mb < 4; ++mb)
#pragma unroll
        for (int nb = 0; nb < 4; ++nb) {
            const int col = n0 + wc * 64 + nb * 16 + lrow;
            const float bv_ = bias ? bias[col] : 0.f;
#pragma unroll
            for (int r = 0; r < 4; ++r) {
                const int row = m0 + wr * 64 + mb * 16 + lgrp * 4 + r;
                const float v = acc[mb][nb][r] + bv_;
                if (OUT_BF16) ((u16*)Cout)[(size_t)row * N + col] = f2bf(v);
                else          ((float*)Cout)[(size_t)row * N + col] = v;
            }
        }
}

// ---------------- RoPE + layout: qkv[t][2560] -> Q[h][t][d], K[kh][t][d], VT[kh][d][t]
__global__ void k_rope(const u16* __restrict__ qkv, const float* __restrict__ cosb,
                       const float* __restrict__ sinb, u16* __restrict__ Q,
                       u16* __restrict__ Kd, u16* __restrict__ VT) {
    const int n = blockIdx.x * 256 + threadIdx.x;   // 0..2559
    const int t = blockIdx.y;
    const u16* row = qkv + (size_t)t * NQKV;
    if (n < 2304) {                                  // q or k: apply RoPE
        const int d = n & 127;
        const float x = bf2f(row[n]);
        const float p = bf2f(row[(d < 64) ? n + 64 : n - 64]);
        const float c = cosb[t * DH + d], s = sinb[t * DH + d];
        const float val = (d < 64) ? (x * c - p * s) : (x * c + p * s);
        const u16 o = f2bf(val);
        if (n < 2048) {
            const int h = n >> 7;
            Q[((size_t)h * T_SEQ + t) * DH + d] = o;
        } else {
            const int kh = (n - 2048) >> 7;
            Kd[((size_t)kh * T_SEQ + t) * DH + d] = o;
        }
    } else {                                         // v: transpose copy
        const int nv = n - 2304;
        const int kh = nv >> 7, d = nv & 127;
        VT[((size_t)kh * DH + d) * T_SEQ + t] = row[n];
    }
}

// ---------------- causal GQA flash attention ----------------
// Block: 4 waves x 32 q-rows = 128 q rows, one q head. KV tile = 64.
// 1D grid of 512 with explicit work-pairing: block g<256 -> q-tile 16+(g>>4),
// block g+256 -> q-tile 15-(g>>4), same head. Under round-robin dispatch
// (block i and i+256 co-resident on one CU at 2 blocks/CU), each CU's pair
// sums to exactly 66 KV-tiles -> no straggler tail.
//
// Bank-conflict fix (T2, rule 21): Ks rows are 256B, VTs rows 128B -> naive
// ds_read_b128 is 16-way conflicted. LDS stays LINEAR (global_load_lds
// requirement); the 16B-unit index is XOR-swizzled by (row&7) on BOTH the
// global source address at staging time and the ds_read address. Involution:
// LDS[row][u] holds global[row][u ^ (row&7)]; reading unit u^(row&7) returns
// global[row][u]. Spreads each 16-lane row-group across all 8 bank quads.
__global__ __launch_bounds__(256, 2) void k_attn(const u16* __restrict__ Q,
                                                 const u16* __restrict__ Kg,
                                                 const u16* __restrict__ VT,
                                                 u16* __restrict__ O) {
    __shared__ u16 Ks[64 * 128];                  // [kv][d], swizzled units
    __shared__ u16 VTs[128 * 64];                 // [d][kv], swizzled units
    __shared__ __align__(16) u16 Pb[4][32][72];   // per-wave P, padded stride 72 (bank-minimal)
    const int tid  = threadIdx.x;
    const int lane = tid & 63, w = tid >> 6;
    const int lrow = lane & 15, lgrp = lane >> 4;
    const int g = blockIdx.x;
    const int h = g & 15, kvh = (g & 15) >> 3;    // GROUPS = 8
    const int qt = (g < 256) ? (16 + (g >> 4)) : (15 - ((g - 256) >> 4));
    const int q0 = qt * 128;
    const int qw = q0 + w * 32;                   // wave's first q row

    // Q fragments in registers: 32 rows x 128 d
    bf16x8 aq[2][4];
#pragma unroll
    for (int mb = 0; mb < 2; ++mb)
#pragma unroll
        for (int kd = 0; kd < 4; ++kd)
            aq[mb][kd] = *(const bf16x8*)&Q[((size_t)h * T_SEQ + qw + mb * 16 + lrow) * DH +
                                            kd * 32 + lgrp * 8];

    f32x4 acc_o[2][8] = {};
    float m_s[2][4], l_s[2][4];
#pragma unroll
    for (int mb = 0; mb < 2; ++mb)
#pragma unroll
        for (int r = 0; r < 4; ++r) { m_s[mb][r] = -1e30f; l_s[mb][r] = 0.f; }

    const u16* Kbase = Kg + (size_t)kvh * T_SEQ * DH;
    const u16* Vbase = VT + (size_t)kvh * DH * T_SEQ;
    const int ntile = q0 / 64 + 2;                // kv < q0+128

    // source pre-swizzle unit indices (match LDS-linear dest rows)
    const int ksw = (tid & 15) ^ ((tid >> 4) & 7);   // K: row&7 = (tid>>4)&7, 16 units/row
    const int vsw = (tid & 7)  ^ ((tid >> 3) & 7);   // VT: row&7 = (tid>>3)&7, 8 units/row

    for (int it = 0; it < ntile; ++it) {
        const int kv0 = it * 64;
        // stage K tile [64][128]: 4 x 16 rows, source col pre-swizzled
#pragma unroll
        for (int c = 0; c < 4; ++c)
            gload_lds16(Kbase + (size_t)(kv0 + c * 16 + (tid >> 4)) * DH + ksw * 8,
                        &Ks[c * 2048 + tid * 8]);
        // stage VT tile [128][64]: 4 x 32 d-rows, source col pre-swizzled
#pragma unroll
        for (int c = 0; c < 4; ++c)
            gload_lds16(Vbase + (size_t)(c * 32 + (tid >> 3)) * T_SEQ + kv0 + vsw * 8,
                        &VTs[c * 2048 + tid * 8]);
        __syncthreads();

        if (kv0 <= qw + 31) {                     // wave has unmasked rows in this tile
            // ---- S = Q K^T : rows q (32), cols kv (64)
            f32x4 sacc[2][4] = {};
            __builtin_amdgcn_s_setprio(1);
#pragma unroll
            for (int kd = 0; kd < 4; ++kd) {
                bf16x8 bk[4];
#pragma unroll
                for (int kvb = 0; kvb < 4; ++kvb)
                    bk[kvb] = *(const bf16x8*)&Ks[(kvb * 16 + lrow) * 128 +
                                                  (((kd * 4 + lgrp) ^ (lrow & 7)) * 8)];
#pragma unroll
                for (int mb = 0; mb < 2; ++mb)
#pragma unroll
                    for (int kvb = 0; kvb < 4; ++kvb)
                        sacc[mb][kvb] = MFMA(aq[mb][kd], bk[kvb], sacc[mb][kvb]);
            }
            __builtin_amdgcn_s_setprio(0);
            const bool needmask = (kv0 + 63) > qw;
            // ---- online softmax, wave-parallel (row = mb*16 + lgrp*4 + r, col = kvb*16+lrow)
#pragma unroll
            for (int mb = 0; mb < 2; ++mb)
#pragma unroll
                for (int r = 0; r < 4; ++r) {
                    float v[4];
#pragma unroll
                    for (int kvb = 0; kvb < 4; ++kvb) v[kvb] = sacc[mb][kvb][r] * SCALE;
                    if (needmask) {
                        const int qrow = qw + mb * 16 + lgrp * 4 + r;
#pragma unroll
                        for (int kvb = 0; kvb < 4; ++kvb)
                            if (kv0 + kvb * 16 + lrow > qrow) v[kvb] = -1e30f;
                    }
                    float pm = fmaxf(fmaxf(v[0], v[1]), fmaxf(v[2], v[3]));
#pragma unroll
                    for (int off = 1; off < 16; off <<= 1)
                        pm = fmaxf(pm, __shfl_xor(pm, off));
                    const float mo = m_s[mb][r];
                    const float mn = fmaxf(mo, pm);
                    const float cc = __expf(mo - mn);
                    float ps = 0.f;
#pragma unroll
                    for (int kvb = 0; kvb < 4; ++kvb) { v[kvb] = __expf(v[kvb] - mn); ps += v[kvb]; }
#pragma unroll
                    for (int off = 1; off < 16; off <<= 1)
                        ps += __shfl_xor(ps, off);
                    m_s[mb][r] = mn;
                    l_s[mb][r] = l_s[mb][r] * cc + ps;
#pragma unroll
                    for (int nb = 0; nb < 8; ++nb) acc_o[mb][nb][r] *= cc;
#pragma unroll
                    for (int kvb = 0; kvb < 4; ++kvb)
                        Pb[w][mb * 16 + lgrp * 4 + r][kvb * 16 + lrow] = f2bf(v[kvb]);
                }
            // ---- PV: O += P[32x64] @ V[64x128]  (wave-local LDS, in-order DS pipe)
            __builtin_amdgcn_s_setprio(1);
#pragma unroll
            for (int ks = 0; ks < 2; ++ks) {
                bf16x8 ap0 = *(const bf16x8*)&Pb[w][lrow][ks * 32 + lgrp * 8];
                bf16x8 ap1 = *(const bf16x8*)&Pb[w][16 + lrow][ks * 32 + lgrp * 8];
#pragma unroll
                for (int nb = 0; nb < 8; ++nb) {
                    bf16x8 bv = *(const bf16x8*)&VTs[(nb * 16 + lrow) * 64 +
                                                     (((ks * 4 + lgrp) ^ (lrow & 7)) * 8)];
                    acc_o[0][nb] = MFMA(ap0, bv, acc_o[0][nb]);
                    acc_o[1][nb] = MFMA(ap1, bv, acc_o[1][nb]);
                }
            }
            __builtin_amdgcn_s_setprio(0);
        }
        __syncthreads();
    }
    // ---- normalize + write O[t][h*128+d] (bf16, feeds output GEMM)
#pragma unroll
    for (int mb = 0; mb < 2; ++mb) {
        float inv[4];
#pragma unroll
        for (int r = 0; r < 4; ++r) inv[r] = 1.0f / l_s[mb][r];
#pragma unroll
        for (int nb = 0; nb < 8; ++nb)
#pragma unroll
            for (int r = 0; r < 4; ++r) {
                const int row = qw + mb * 16 + lgrp * 4 + r;
                const int col = h * DH + nb * 16 + lrow;
                O[(size_t)row * HID + col] = f2bf(acc_o[mb][nb][r] * inv[r]);
            }
    }
}

// ---------------- launch ----------------
extern "C" void kernel_launch(void* const* d_in, const int* in_sizes, int n_in,
                              void* d_out, int out_size, void* d_ws, size_t ws_size,
                              hipStream_t stream) {
    const float* x    = (const float*)d_in[0];
    const float* cosb = (const float*)d_in[1];
    const float* sinb = (const float*)d_in[2];
    const float* wq   = (const float*)d_in[3];
    const float* bq   = (const float*)d_in[4];
    const float* wk   = (const float*)d_in[5];
    const float* bk   = (const float*)d_in[6];
    const float* wv   = (const float*)d_in[7];
    const float* bv   = (const float*)d_in[8];
    const float* wo   = (const float*)d_in[9];
    float* out = (float*)d_out;

    char* ws = (char*)d_ws;
    // workspace layout (bytes), peak ~58 MB via aliasing:
    //   [0]          x_bf   16,777,216   -> reused as Qb after GEMM1
    //   [16,777,216] wqkv_bf 10,485,760
    //   [27,262,976] wo_bf   8,388,608
    //   [35,651,584] bias       10,240 (pad to 16,384)
    //   [35,667,968] qkv    20,971,520   -> reused as Ob after rope
    //   [56,639,488] Kb      2,097,152
    //   [58,736,640] VTb     2,097,152   -> end 60,833,792
    u16*   x_bf    = (u16*)(ws);
    u16*   Qb      = (u16*)(ws);                       // alias: x_bf dead after GEMM1
    u16*   wqkv_bf = (u16*)(ws + 16777216);
    u16*   wo_bf   = (u16*)(ws + 27262976);
    float* bias    = (float*)(ws + 35651584);
    u16*   qkv     = (u16*)(ws + 35667968);
    u16*   Ob      = (u16*)(ws + 35667968);            // alias: qkv dead after rope
    u16*   Kb      = (u16*)(ws + 56639488);
    u16*   VTb     = (u16*)(ws + 58736640);

    // fp32 -> bf16 (x, wq, wk, wv, wo) in one launch + bias concat
    k_cvt_all<<<17408, 256, 0, stream>>>((const float4*)x, (const float4*)wq,
                                         (const float4*)wk, (const float4*)wv,
                                         (const float4*)wo, x_bf, wqkv_bf, wo_bf);
    k_bias<<<10, 256, 0, stream>>>(bq, bk, bv, bias);

    // QKV projection (+bias): [4096,2048] @ [2560,2048]^T -> bf16 [4096,2560]
    k_gemm_bt<1><<<dim3(32, 20), 256, 0, stream>>>(x_bf, wqkv_bf, bias, qkv, 4096, 2560, 2048);
    // RoPE + attention layouts
    k_rope<<<dim3(10, 4096), 256, 0, stream>>>(qkv, cosb, sinb, Qb, Kb, VTb);
    // flash attention (balanced 1D grid)
    k_attn<<<512, 256, 0, stream>>>(Qb, Kb, VTb, Ob);
    // output projection: [4096,2048] @ [2048,2048]^T -> fp32 d_out
    k_gemm_bt<0><<<dim3(32, 16), 256, 0, stream>>>(Ob, wo_bf, nullptr, out, 4096, 2048, 2048);
}

// Round 9
// 409.062 us; speedup vs baseline: 1.2775x; 1.2775x over previous
//
#include <hip/hip_runtime.h>
#include <hip/hip_bf16.h>
#include <stdint.h>

// Problem constants (from reference): B=1, T=4096, HID=2048, NQ=16, NKV=2, D=128
#define T_SEQ 4096
#define HID   2048
#define NQH   16
#define NKVH  2
#define DH    128
#define NQKV  2560   // 2048 (q) + 256 (k) + 256 (v)
#define SCALE 0.08838834764831845f
// softmax runs in exp2 domain: fold SCALE*log2(e) into Q at rope time
#define QK_PRESCALE (0.08838834764831845f * 1.4426950408889634f)

typedef unsigned short u16;
typedef __attribute__((ext_vector_type(8))) short bf16x8;   // 8 bf16 = 4 VGPR
typedef __attribute__((ext_vector_type(4))) float f32x4;

#define MFMA(a, b, c) __builtin_amdgcn_mfma_f32_16x16x32_bf16(a, b, c, 0, 0, 0)

static __device__ __forceinline__ u16 f2bf(float f) {
    union { float f; uint32_t u; } v; v.f = f;
    uint32_t r = v.u + 0x7fffu + ((v.u >> 16) & 1u);   // RNE
    return (u16)(r >> 16);
}
static __device__ __forceinline__ float bf2f(u16 u) {
    union { uint32_t u; float f; } v; v.u = ((uint32_t)u) << 16;
    return v.f;
}

// async global->LDS, 16B per lane. LDS dest must be linear in lane order.
static __device__ __forceinline__ void gload_lds16(const void* g, void* l) {
    __builtin_amdgcn_global_load_lds((const __attribute__((address_space(1))) uint32_t*)g,
                                     (__attribute__((address_space(3))) uint32_t*)l,
                                     16, 0, 0);
}

// ---------------- fp32 -> bf16 convert, all 5 tensors in one exact-grid launch ---------
// f4-unit segment bounds: x[0,2097152) wq[..3145728) wk[..3276800) wv[..3407872) wo[..4456448)
__global__ void k_cvt_all(const float4* __restrict__ x,  const float4* __restrict__ wq,
                          const float4* __restrict__ wk, const float4* __restrict__ wv,
                          const float4* __restrict__ wo,
                          u16* __restrict__ x_bf, u16* __restrict__ wqkv_bf,
                          u16* __restrict__ wo_bf) {
    const int i = blockIdx.x * 256 + threadIdx.x;
    const float4* src; u16* dst; int off;
    if (i < 2097152)      { src = x;  dst = x_bf;              off = i; }
    else if (i < 3145728) { src = wq; dst = wqkv_bf;           off = i - 2097152; }
    else if (i < 3276800) { src = wk; dst = wqkv_bf + 4194304; off = i - 3145728; }
    else if (i < 3407872) { src = wv; dst = wqkv_bf + 4718592; off = i - 3276800; }
    else                  { src = wo; dst = wo_bf;             off = i - 3407872; }
    const float4 v = src[off];
    const uint64_t o = (uint64_t)f2bf(v.x) | ((uint64_t)f2bf(v.y) << 16) |
                       ((uint64_t)f2bf(v.z) << 32) | ((uint64_t)f2bf(v.w) << 48);
    *(uint64_t*)(dst + (size_t)off * 4) = o;
}

// ---------------- bias concat (bq|bk|bv), fp32 ----------------
__global__ void k_bias(const float* __restrict__ bq, const float* __restrict__ bk,
                       const float* __restrict__ bv, float* __restrict__ out) {
    int i = blockIdx.x * 256 + threadIdx.x;          // 0..2559
    float v = (i < 2048) ? bq[i] : (i < 2304 ? bk[i - 2048] : bv[i - 2304]);
    out[i] = v;
}

// ---------------- GEMM: C[M,N] = A[M,K] @ B[N,K]^T (+bias), m97 structure ----------
template <int OUT_BF16>
__global__ __launch_bounds__(256, 2) void k_gemm_bt(const u16* __restrict__ A,
                                                    const u16* __restrict__ B,
                                                    const float* __restrict__ bias,
                                                    void* __restrict__ Cout,
                                                    int M, int N, int K) {
    __shared__ u16 As[128 * 32];
    __shared__ u16 Bs[128 * 32];
    const int tid  = threadIdx.x;
    const int lane = tid & 63, w = tid >> 6;
    const int wr = w >> 1, wc = w & 1;
    const int lrow = lane & 15, lgrp = lane >> 4;
    const int m0 = blockIdx.x * 128, n0 = blockIdx.y * 128;

    f32x4 acc[4][4] = {};
    const int arow = tid >> 2, acol = (tid & 3) * 8;   // staging: 64 rows/instr
    const u16* Abase = A + (size_t)(m0 + arow) * K + acol;
    const u16* Bbase = B + (size_t)(n0 + arow) * K + acol;

    for (int kk = 0; kk < K; kk += 32) {
        gload_lds16(Abase + kk,                   &As[tid * 8]);
        gload_lds16(Abase + kk + (size_t)64 * K,  &As[2048 + tid * 8]);
        gload_lds16(Bbase + kk,                   &Bs[tid * 8]);
        gload_lds16(Bbase + kk + (size_t)64 * K,  &Bs[2048 + tid * 8]);
        __syncthreads();
        bf16x8 af[4], bfv[4];
#pragma unroll
        for (int mb = 0; mb < 4; ++mb)
            af[mb] = *(const bf16x8*)&As[(wr * 64 + mb * 16 + lrow) * 32 + lgrp * 8];
#pragma unroll
        for (int nb = 0; nb < 4; ++nb)
            bfv[nb] = *(const bf16x8*)&Bs[(wc * 64 + nb * 16 + lrow) * 32 + lgrp * 8];
#pragma unroll
        for (int mb = 0; mb < 4; ++mb)
#pragma unroll
            for (int nb = 0; nb < 4; ++nb)
                acc[mb][nb] = MFMA(af[mb], bfv[nb], acc[mb][nb]);
        __syncthreads();
    }
#pragma unroll
    for (int mb = 0; mb < 4; ++mb)
#pragma unroll
        for (int nb = 0; nb < 4; ++nb) {
            const int col = n0 + wc * 64 + nb * 16 + lrow;
            const float bv_ = bias ? bias[col] : 0.f;
#pragma unroll
            for (int r = 0; r < 4; ++r) {
                const int row = m0 + wr * 64 + mb * 16 + lgrp * 4 + r;
                const float v = acc[mb][nb][r] + bv_;
                if (OUT_BF16) ((u16*)Cout)[(size_t)row * N + col] = f2bf(v);
                else          ((float*)Cout)[(size_t)row * N + col] = v;
            }
        }
}

// ---------------- RoPE + layout ----------------
// qkv[t][2560] -> Q[h][t][d] (pre-scaled by SCALE*log2e),
//                 Kswz[kh][t][*]  (16B-unit XOR-swizzled by t&7, baked into global),
//                 VTp[kh][d][*]   (kv-permuted within 64-tiles AND XOR-swizzled by d&7).
// kv permutation pi: stored col c within a 64-tile holds physical kappa(c)=(c&3)*16+(c>>2);
// inverse: c = (kappa&15)*4 + (kappa>>4). P-tiles in k_attn are stored in the same c-order,
// so PV contracts consistently (sum over kv is order-invariant).
__global__ void k_rope(const u16* __restrict__ qkv, const float* __restrict__ cosb,
                       const float* __restrict__ sinb, u16* __restrict__ Q,
                       u16* __restrict__ Kd, u16* __restrict__ VT) {
    const int n = blockIdx.x * 256 + threadIdx.x;   // 0..2559
    const int t = blockIdx.y;
    const u16* row = qkv + (size_t)t * NQKV;
    if (n < 2304) {                                  // q or k: apply RoPE
        const int d = n & 127;
        const float x = bf2f(row[n]);
        const float p = bf2f(row[(d < 64) ? n + 64 : n - 64]);
        const float c = cosb[t * DH + d], s = sinb[t * DH + d];
        float val = (d < 64) ? (x * c - p * s) : (x * c + p * s);
        if (n < 2048) {
            const int h = n >> 7;
            Q[((size_t)h * T_SEQ + t) * DH + d] = f2bf(val * QK_PRESCALE);
        } else {
            const int kh = (n - 2048) >> 7;
            const int u = (d >> 3) ^ (t & 7);        // bake read-side swizzle
            Kd[((size_t)kh * T_SEQ + t) * DH + u * 8 + (d & 7)] = f2bf(val);
        }
    } else {                                         // v: permuted+swizzled transpose
        const int nv = n - 2304;
        const int kh = nv >> 7, d = nv & 127;
        const int kappa = t & 63;
        const int c = (kappa & 15) * 4 + (kappa >> 4);
        const int u = (c >> 3) ^ (d & 7);            // bake read-side swizzle
        VT[((size_t)kh * DH + d) * T_SEQ + (t & ~63) + u * 8 + (c & 7)] = row[n];
    }
}

// ---------------- causal GQA flash attention ----------------
// 512 blocks, 2/CU (57 KB LDS). Block g: head h=g&15, pair pp=g>>4; runs q-tile
// (63-pp) then pp (QBLK=64, 4 waves x 16 rows) -> exactly 65 KV-tile iterations
// per block. K double-buffered, V single-buffered: per iter stage [V(it+1),
// K(it+2)] after the trailing barrier; steady-state wait vmcnt(4) keeps K(it+2)
// in flight (T3/T4). Softmax: exp2-domain (scale folded into Q), per-lane l
// partials (reduced at epilogue), T13 defer-max, P packed via v_cvt_pk_bf16_f32
// + one ds_write_b64 per row in pi-order.
__global__ __launch_bounds__(256, 2) void k_attn(const u16* __restrict__ Q,
                                                 const u16* __restrict__ Kg,
                                                 const u16* __restrict__ VT,
                                                 u16* __restrict__ O) {
    __shared__ u16 Ks[2][64 * 128];               // [buf][kv][d-swizzled]  32 KB
    __shared__ u16 VTs[64 * 128];                 // [d][c-swizzled] 128 rows x 64  16 KB
    __shared__ __align__(16) u16 Pb[4][16][72];   // per-wave P, c-order, stride 72  9 KB
    const int tid  = threadIdx.x;
    const int lane = tid & 63, w = tid >> 6;
    const int lrow = lane & 15, lgrp = lane >> 4;
    const int g = blockIdx.x;
    const int h = g & 15, pp = g >> 4;            // pair index 0..31
    const int kvh = h >> 3;                       // GROUPS = 8

    const u16* Kbase = Kg + (size_t)kvh * T_SEQ * DH;
    const u16* Vbase = VT + (size_t)kvh * DH * T_SEQ;

    auto STAGE_K = [&](int buf, int it) {
        const u16* kg = Kbase + (size_t)(it * 64 + (tid >> 4)) * DH + (tid & 15) * 8;
#pragma unroll
        for (int c = 0; c < 4; ++c)
            gload_lds16(kg + (size_t)c * 16 * DH, &Ks[buf][c * 2048 + tid * 8]);
    };
    auto STAGE_V = [&](int it) {
        const u16* vg = Vbase + (size_t)(tid >> 3) * T_SEQ + it * 64 + (tid & 7) * 8;
#pragma unroll
        for (int c = 0; c < 4; ++c)
            gload_lds16(vg + (size_t)c * 32 * T_SEQ, &VTs[c * 2048 + tid * 8]);
    };

    for (int ph = 0; ph < 2; ++ph) {
        const int qt = ph ? pp : (63 - pp);       // heavy q-tile first
        const int q0 = qt * 64;
        const int qw = q0 + w * 16;               // wave's first q row

        bf16x8 aq[4];
#pragma unroll
        for (int kd = 0; kd < 4; ++kd)
            aq[kd] = *(const bf16x8*)&Q[((size_t)h * T_SEQ + qw + lrow) * DH +
                                        kd * 32 + lgrp * 8];

        f32x4 acc_o[8] = {};
        float m_s[4], l_s[4];
#pragma unroll
        for (int r = 0; r < 4; ++r) { m_s[r] = -1e30f; l_s[r] = 0.f; }

        // tiles 0..qt (kv < q0+64). Prologue: K0, V0, K1 (K1 harmless if qt==0).
        STAGE_K(0, 0);
        STAGE_V(0);
        STAGE_K(1, 1);

        for (int it = 0; it <= qt; ++it) {
            const int cur = it & 1;
            // steady state outstanding: K(it)[4], V(it)[4], K(it+1)[4?]
            if (it < qt) asm volatile("s_waitcnt vmcnt(4)" ::: "memory");
            else         asm volatile("s_waitcnt vmcnt(0)" ::: "memory");
            __builtin_amdgcn_s_barrier();
            const int kv0 = it * 64;

            // ---- S = Q K^T : rows q (16), cols kv (64), exp2-domain pre-scaled
            f32x4 sacc[4] = {};
#pragma unroll
            for (int kd = 0; kd < 4; ++kd) {
                bf16x8 bk[4];
#pragma unroll
                for (int kvb = 0; kvb < 4; ++kvb)
                    bk[kvb] = *(const bf16x8*)&Ks[cur][(kvb * 16 + lrow) * 128 +
                                                      (((kd * 4 + lgrp) ^ (lrow & 7)) * 8)];
#pragma unroll
                for (int kvb = 0; kvb < 4; ++kvb)
                    sacc[kvb] = MFMA(aq[kd], bk[kvb], sacc[kvb]);
            }
            const bool needmask = (it == qt);     // only the diagonal tile masks
            // ---- online softmax (row = lgrp*4+r, col = kvb*16+lrow)
#pragma unroll
            for (int r = 0; r < 4; ++r) {
                float v[4];
#pragma unroll
                for (int kvb = 0; kvb < 4; ++kvb) v[kvb] = sacc[kvb][r];
                if (needmask) {
                    const int qrow = qw + lgrp * 4 + r;
#pragma unroll
                    for (int kvb = 0; kvb < 4; ++kvb)
                        if (kv0 + kvb * 16 + lrow > qrow) v[kvb] = -1e30f;
                }
                float pm = fmaxf(fmaxf(v[0], v[1]), fmaxf(v[2], v[3]));
#pragma unroll
                for (int off = 1; off < 16; off <<= 1)
                    pm = fmaxf(pm, __shfl_xor(pm, off));
                // T13 defer-max: skip rescale while max growth <= 8 (exp2 domain)
                if (!__all(pm <= m_s[r] + 8.0f)) {
                    const float mo = m_s[r];
                    const float mn = fmaxf(mo, pm);
                    const float cc = exp2f(mo - mn);
                    l_s[r] *= cc;
#pragma unroll
                    for (int nb = 0; nb < 8; ++nb) acc_o[nb][r] *= cc;
                    m_s[r] = mn;
                }
                const float mm = m_s[r];
                float ps = 0.f;
#pragma unroll
                for (int kvb = 0; kvb < 4; ++kvb) {
                    v[kvb] = exp2f(v[kvb] - mm);
                    ps += v[kvb];
                }
                l_s[r] += ps;                     // per-lane partial; reduced at epilogue
                uint32_t pk0, pk1;                // pack P row in pi-order: cols lrow*4+{0..3}
                asm("v_cvt_pk_bf16_f32 %0, %1, %2" : "=v"(pk0) : "v"(v[0]), "v"(v[1]));
                asm("v_cvt_pk_bf16_f32 %0, %1, %2" : "=v"(pk1) : "v"(v[2]), "v"(v[3]));
                *(uint2*)&Pb[w][lgrp * 4 + r][lrow * 4] = make_uint2(pk0, pk1);
            }
            // ---- PV: O += P'[16x64c] @ V'[64c x128] (both in pi-order)
#pragma unroll
            for (int ks = 0; ks < 2; ++ks) {
                bf16x8 ap = *(const bf16x8*)&Pb[w][lrow][ks * 32 + lgrp * 8];
#pragma unroll
                for (int nb = 0; nb < 8; ++nb) {
                    bf16x8 bv = *(const bf16x8*)&VTs[(nb * 16 + lrow) * 64 +
                                                     (((ks * 4 + lgrp) ^ (lrow & 7)) * 8)];
                    acc_o[nb] = MFMA(ap, bv, acc_o[nb]);
                }
            }
            __builtin_amdgcn_s_barrier();
            // stage next V (single buffer: all PV reads done) and next-next K
            if (it + 1 <= qt) {
                STAGE_V(it + 1);
                if (it + 2 <= qt) STAGE_K(cur, it + 2);
            }
        }

        // ---- epilogue: reduce per-lane l partials, normalize, write O[t][h*128+d]
        float inv[4];
#pragma unroll
        for (int r = 0; r < 4; ++r) {
            float lv = l_s[r];
#pragma unroll
            for (int off = 1; off < 16; off <<= 1)
                lv += __shfl_xor(lv, off);
            inv[r] = 1.0f / lv;
        }
#pragma unroll
        for (int nb = 0; nb < 8; ++nb)
#pragma unroll
            for (int r = 0; r < 4; ++r) {
                const int row = qw + lgrp * 4 + r;
                const int col = h * DH + nb * 16 + lrow;
                O[(size_t)row * HID + col] = f2bf(acc_o[nb][r] * inv[r]);
            }
    }
}

// ---------------- launch ----------------
extern "C" void kernel_launch(void* const* d_in, const int* in_sizes, int n_in,
                              void* d_out, int out_size, void* d_ws, size_t ws_size,
                              hipStream_t stream) {
    const float* x    = (const float*)d_in[0];
    const float* cosb = (const float*)d_in[1];
    const float* sinb = (const float*)d_in[2];
    const float* wq   = (const float*)d_in[3];
    const float* bq   = (const float*)d_in[4];
    const float* wk   = (const float*)d_in[5];
    const float* bk   = (const float*)d_in[6];
    const float* wv   = (const float*)d_in[7];
    const float* bv   = (const float*)d_in[8];
    const float* wo   = (const float*)d_in[9];
    float* out = (float*)d_out;

    char* ws = (char*)d_ws;
    u16*   x_bf    = (u16*)(ws);
    u16*   Qb      = (u16*)(ws);                       // alias: x_bf dead after GEMM1
    u16*   wqkv_bf = (u16*)(ws + 16777216);
    u16*   wo_bf   = (u16*)(ws + 27262976);
    float* bias    = (float*)(ws + 35651584);
    u16*   qkv     = (u16*)(ws + 35667968);
    u16*   Ob      = (u16*)(ws + 35667968);            // alias: qkv dead after rope
    u16*   Kb      = (u16*)(ws + 56639488);
    u16*   VTb     = (u16*)(ws + 58736640);

    k_cvt_all<<<17408, 256, 0, stream>>>((const float4*)x, (const float4*)wq,
                                         (const float4*)wk, (const float4*)wv,
                                         (const float4*)wo, x_bf, wqkv_bf, wo_bf);
    k_bias<<<10, 256, 0, stream>>>(bq, bk, bv, bias);

    // QKV projection (+bias): [4096,2048] @ [2560,2048]^T -> bf16 [4096,2560]
    k_gemm_bt<1><<<dim3(32, 20), 256, 0, stream>>>(x_bf, wqkv_bf, bias, qkv, 4096, 2560, 2048);
    // RoPE + attention layouts (Q pre-scaled; K/V pre-swizzled/permuted)
    k_rope<<<dim3(10, 4096), 256, 0, stream>>>(qkv, cosb, sinb, Qb, Kb, VTb);
    // flash attention: 512 equal-work blocks (two q-tiles each), 2 blocks/CU
    k_attn<<<512, 256, 0, stream>>>(Qb, Kb, VTb, Ob);
    // output projection: [4096,2048] @ [2048,2048]^T -> fp32 d_out
    k_gemm_bt<0><<<dim3(32, 16), 256, 0, stream>>>(Ob, wo_bf, nullptr, out, 4096, 2048, 2048);
}

// Round 10
// 359.174 us; speedup vs baseline: 1.4549x; 1.1389x over previous
//
#include <hip/hip_runtime.h>
#include <hip/hip_bf16.h>
#include <stdint.h>

// Problem constants (from reference): B=1, T=4096, HID=2048, NQ=16, NKV=2, D=128
#define T_SEQ 4096
#define HID   2048
#define NQH   16
#define NKVH  2
#define DH    128
#define NQKV  2560   // 2048 (q) + 256 (k) + 256 (v)
// softmax runs in exp2 domain: fold SCALE*log2(e) into Q at rope time
#define QK_PRESCALE (0.08838834764831845f * 1.4426950408889634f)

typedef unsigned short u16;
typedef __attribute__((ext_vector_type(8))) short bf16x8;   // 8 bf16 = 4 VGPR
typedef __attribute__((ext_vector_type(4))) float f32x4;

#define MFMA(a, b, c) __builtin_amdgcn_mfma_f32_16x16x32_bf16(a, b, c, 0, 0, 0)

static __device__ __forceinline__ u16 f2bf(float f) {
    union { float f; uint32_t u; } v; v.f = f;
    uint32_t r = v.u + 0x7fffu + ((v.u >> 16) & 1u);   // RNE
    return (u16)(r >> 16);
}
static __device__ __forceinline__ float bf2f(u16 u) {
    union { uint32_t u; float f; } v; v.u = ((uint32_t)u) << 16;
    return v.f;
}

// async global->LDS, 16B per lane. LDS dest must be linear in lane order.
static __device__ __forceinline__ void gload_lds16(const void* g, void* l) {
    __builtin_amdgcn_global_load_lds((const __attribute__((address_space(1))) uint32_t*)g,
                                     (__attribute__((address_space(3))) uint32_t*)l,
                                     16, 0, 0);
}

// ---------------- fp32 -> bf16 convert, all 5 tensors in one exact-grid launch ---------
// f4-unit segment bounds: x[0,2097152) wq[..3145728) wk[..3276800) wv[..3407872) wo[..4456448)
__global__ void k_cvt_all(const float4* __restrict__ x,  const float4* __restrict__ wq,
                          const float4* __restrict__ wk, const float4* __restrict__ wv,
                          const float4* __restrict__ wo,
                          u16* __restrict__ x_bf, u16* __restrict__ wqkv_bf,
                          u16* __restrict__ wo_bf) {
    const int i = blockIdx.x * 256 + threadIdx.x;
    const float4* src; u16* dst; int off;
    if (i < 2097152)      { src = x;  dst = x_bf;              off = i; }
    else if (i < 3145728) { src = wq; dst = wqkv_bf;           off = i - 2097152; }
    else if (i < 3276800) { src = wk; dst = wqkv_bf + 4194304; off = i - 3145728; }
    else if (i < 3407872) { src = wv; dst = wqkv_bf + 4718592; off = i - 3276800; }
    else                  { src = wo; dst = wo_bf;             off = i - 3407872; }
    const float4 v = src[off];
    const uint64_t o = (uint64_t)f2bf(v.x) | ((uint64_t)f2bf(v.y) << 16) |
                       ((uint64_t)f2bf(v.z) << 32) | ((uint64_t)f2bf(v.w) << 48);
    *(uint64_t*)(dst + (size_t)off * 4) = o;
}

// ---------------- bias concat (bq|bk|bv), fp32 ----------------
__global__ void k_bias(const float* __restrict__ bq, const float* __restrict__ bk,
                       const float* __restrict__ bv, float* __restrict__ out) {
    int i = blockIdx.x * 256 + threadIdx.x;          // 0..2559
    float v = (i < 2048) ? bq[i] : (i < 2304 ? bk[i - 2048] : bv[i - 2304]);
    out[i] = v;
}

// ---------------- GEMM: C[M,N] = A[M,K] @ B[N,K]^T (+bias), m97 structure ----------
template <int OUT_BF16>
__global__ __launch_bounds__(256, 2) void k_gemm_bt(const u16* __restrict__ A,
                                                    const u16* __restrict__ B,
                                                    const float* __restrict__ bias,
                                                    void* __restrict__ Cout,
                                                    int M, int N, int K) {
    __shared__ u16 As[128 * 32];
    __shared__ u16 Bs[128 * 32];
    const int tid  = threadIdx.x;
    const int lane = tid & 63, w = tid >> 6;
    const int wr = w >> 1, wc = w & 1;
    const int lrow = lane & 15, lgrp = lane >> 4;
    const int m0 = blockIdx.x * 128, n0 = blockIdx.y * 128;

    f32x4 acc[4][4] = {};
    const int arow = tid >> 2, acol = (tid & 3) * 8;   // staging: 64 rows/instr
    const u16* Abase = A + (size_t)(m0 + arow) * K + acol;
    const u16* Bbase = B + (size_t)(n0 + arow) * K + acol;

    for (int kk = 0; kk < K; kk += 32) {
        gload_lds16(Abase + kk,                   &As[tid * 8]);
        gload_lds16(Abase + kk + (size_t)64 * K,  &As[2048 + tid * 8]);
        gload_lds16(Bbase + kk,                   &Bs[tid * 8]);
        gload_lds16(Bbase + kk + (size_t)64 * K,  &Bs[2048 + tid * 8]);
        __syncthreads();
        bf16x8 af[4], bfv[4];
#pragma unroll
        for (int mb = 0; mb < 4; ++mb)
            af[mb] = *(const bf16x8*)&As[(wr * 64 + mb * 16 + lrow) * 32 + lgrp * 8];
#pragma unroll
        for (int nb = 0; nb < 4; ++nb)
            bfv[nb] = *(const bf16x8*)&Bs[(wc * 64 + nb * 16 + lrow) * 32 + lgrp * 8];
#pragma unroll
        for (int mb = 0; mb < 4; ++mb)
#pragma unroll
            for (int nb = 0; nb < 4; ++nb)
                acc[mb][nb] = MFMA(af[mb], bfv[nb], acc[mb][nb]);
        __syncthreads();
    }
#pragma unroll
    for (int mb = 0; mb < 4; ++mb)
#pragma unroll
        for (int nb = 0; nb < 4; ++nb) {
            const int col = n0 + wc * 64 + nb * 16 + lrow;
            const float bv_ = bias ? bias[col] : 0.f;
#pragma unroll
            for (int r = 0; r < 4; ++r) {
                const int row = m0 + wr * 64 + mb * 16 + lgrp * 4 + r;
                const float v = acc[mb][nb][r] + bv_;
                if (OUT_BF16) ((u16*)Cout)[(size_t)row * N + col] = f2bf(v);
                else          ((float*)Cout)[(size_t)row * N + col] = v;
            }
        }
}

// ---------------- RoPE + layout ----------------
// qkv[t][2560] -> Q[h][t][d] (pre-scaled by SCALE*log2e),
//                 Kswz[kh][t][*]  (16B-unit XOR-swizzled by t&7, baked into global),
//                 VTp[kh][d][*]   (kv tau-permuted within 64-tiles AND XOR-swizzled by d&7).
// tau: PV contracts in sigma-order sigma(32ks+8kg+j) = 16*(2ks+(j>>2)) + 4kg + (j&3),
// which makes the in-register P B-fragment lane-local in k_attn. Stored col c for
// physical kv=kappa: c = (kappa&0x20) | ((kappa&0xC)<<1) | ((kappa&0x10)>>2) | (kappa&3).
__global__ void k_rope(const u16* __restrict__ qkv, const float* __restrict__ cosb,
                       const float* __restrict__ sinb, u16* __restrict__ Q,
                       u16* __restrict__ Kd, u16* __restrict__ VT) {
    const int n = blockIdx.x * 256 + threadIdx.x;   // 0..2559
    const int t = blockIdx.y;
    const u16* row = qkv + (size_t)t * NQKV;
    if (n < 2304) {                                  // q or k: apply RoPE
        const int d = n & 127;
        const float x = bf2f(row[n]);
        const float p = bf2f(row[(d < 64) ? n + 64 : n - 64]);
        const float c = cosb[t * DH + d], s = sinb[t * DH + d];
        float val = (d < 64) ? (x * c - p * s) : (x * c + p * s);
        if (n < 2048) {
            const int h = n >> 7;
            Q[((size_t)h * T_SEQ + t) * DH + d] = f2bf(val * QK_PRESCALE);
        } else {
            const int kh = (n - 2048) >> 7;
            const int u = (d >> 3) ^ (t & 7);        // bake read-side swizzle
            Kd[((size_t)kh * T_SEQ + t) * DH + u * 8 + (d & 7)] = f2bf(val);
        }
    } else {                                         // v: tau-permuted + swizzled transpose
        const int nv = n - 2304;
        const int kh = nv >> 7, d = nv & 127;
        const int kappa = t & 63;
        const int c = (kappa & 0x20) | ((kappa & 0xC) << 1) | ((kappa & 0x10) >> 2) | (kappa & 3);
        const int u = (c >> 3) ^ (d & 7);            // bake read-side swizzle
        VT[((size_t)kh * DH + d) * T_SEQ + (t & ~63) + u * 8 + (c & 7)] = row[n];
    }
}

// ---------------- causal GQA flash attention ----------------
// 1024 blocks (16 heads x 64 q-tiles of 64 rows), heavy tiles dispatched first;
// 48 KB LDS -> 3 blocks/CU resident, remainder queues -> LPT-style balancing.
// Swapped QK^T: MFMA(K,Q) -> lane holds S^T: q = lane&15, kv = kvb*16 + (lane>>4)*4 + r.
// Softmax per-lane over 16 values: 15 fmax + 2 shfl; m,l are per-lane scalars.
// P never touches LDS: PV contracts in sigma-order so the B-frag is 4 lane-local
// cvt_pk words; V's global layout bakes the matching tau (see k_rope).
// PV also swapped: MFMA(V^T, P) -> acc holds O^T (d rows, q col), 8B epilogue stores.
// K dbuf + V single-buffer staging with counted vmcnt (identical ledger to r5/passed).
__global__ __launch_bounds__(256, 3) void k_attn(const u16* __restrict__ Q,
                                                 const u16* __restrict__ Kg,
                                                 const u16* __restrict__ VT,
                                                 u16* __restrict__ O) {
    __shared__ u16 Ks[2][64 * 128];               // [buf][kv][d-swizzled]  32 KB
    __shared__ u16 VTs[64 * 128];                 // [d][c-swizzled] 128 rows x 64  16 KB
    const int tid  = threadIdx.x;
    const int lane = tid & 63, w = tid >> 6;
    const int ql = lane & 15, kg = lane >> 4;     // q-col / kv-quad group
    const int g = blockIdx.x;
    const int h = g & 15, qt = 63 - (g >> 4);     // heavy q-tiles first
    const int kvh = h >> 3;                       // GROUPS = 8
    const int q0 = qt * 64;
    const int qw = q0 + w * 16;                   // wave's first q row

    const u16* Kbase = Kg + (size_t)kvh * T_SEQ * DH;
    const u16* Vbase = VT + (size_t)kvh * DH * T_SEQ;

    auto STAGE_K = [&](int buf, int it) {
        const u16* kg_ = Kbase + (size_t)(it * 64 + (tid >> 4)) * DH + (tid & 15) * 8;
#pragma unroll
        for (int c = 0; c < 4; ++c)
            gload_lds16(kg_ + (size_t)c * 16 * DH, &Ks[buf][c * 2048 + tid * 8]);
    };
    auto STAGE_V = [&](int it) {
        const u16* vg = Vbase + (size_t)(tid >> 3) * T_SEQ + it * 64 + (tid & 7) * 8;
#pragma unroll
        for (int c = 0; c < 4; ++c)
            gload_lds16(vg + (size_t)c * 32 * T_SEQ, &VTs[c * 2048 + tid * 8]);
    };

    // Q fragments (B-operand): lane ql = q row, kg = k-slice
    bf16x8 aq[4];
#pragma unroll
    for (int kd = 0; kd < 4; ++kd)
        aq[kd] = *(const bf16x8*)&Q[((size_t)h * T_SEQ + qw + ql) * DH + kd * 32 + kg * 8];

    f32x4 acc_o[8] = {};                          // O^T: d = nb*16 + kg*4 + r, q = ql
    float m_s = -1e30f, l_s = 0.f;

    // Prologue: K0, V0, K1 (K1 reads tile 1: rows < T always, harmless if qt==0).
    STAGE_K(0, 0);
    STAGE_V(0);
    STAGE_K(1, 1);

    for (int it = 0; it <= qt; ++it) {
        const int cur = it & 1;
        // steady state outstanding: K(it)[4], V(it)[4], K(it+1)[4]
        if (it < qt) asm volatile("s_waitcnt vmcnt(4)" ::: "memory");
        else         asm volatile("s_waitcnt vmcnt(0)" ::: "memory");
        __builtin_amdgcn_s_barrier();
        const int kv0 = it * 64;

        // ---- S^T = K Q^T : lane holds S[kv = kv0+kvb*16+kg*4+r][q = qw+ql]
        f32x4 sacc[4] = {};
#pragma unroll
        for (int kd = 0; kd < 4; ++kd) {
            bf16x8 bk[4];
#pragma unroll
            for (int kvb = 0; kvb < 4; ++kvb)
                bk[kvb] = *(const bf16x8*)&Ks[cur][(kvb * 16 + ql) * 128 +
                                                  (((kd * 4 + kg) ^ (ql & 7)) * 8)];
#pragma unroll
            for (int kvb = 0; kvb < 4; ++kvb)
                sacc[kvb] = MFMA(bk[kvb], aq[kd], sacc[kvb]);   // swapped: A=K, B=Q
        }
        // ---- mask (diagonal tile only)
        if (it == qt) {
            const int thr = qw + ql - kv0 - kg * 4;   // mask if kvb*16 + r > thr
#pragma unroll
            for (int kvb = 0; kvb < 4; ++kvb)
#pragma unroll
                for (int r = 0; r < 4; ++r)
                    if (kvb * 16 + r > thr) sacc[kvb][r] = -1e30f;
        }
        // ---- per-lane softmax over 16 values; row spans 4 kg-lanes
        float pm = -1e30f;
#pragma unroll
        for (int kvb = 0; kvb < 4; ++kvb)
#pragma unroll
            for (int r = 0; r < 4; ++r) pm = fmaxf(pm, sacc[kvb][r]);
        pm = fmaxf(pm, __shfl_xor(pm, 16));
        pm = fmaxf(pm, __shfl_xor(pm, 32));
        // T13 defer-max: skip rescale while max growth <= 8 (exp2 domain)
        if (!__all(pm <= m_s + 8.0f)) {
            const float mn = fmaxf(m_s, pm);
            const float cc = exp2f(m_s - mn);
            l_s *= cc;
#pragma unroll
            for (int nb = 0; nb < 8; ++nb)
#pragma unroll
                for (int r = 0; r < 4; ++r) acc_o[nb][r] *= cc;
            m_s = mn;
        }
        float ps = 0.f;
#pragma unroll
        for (int kvb = 0; kvb < 4; ++kvb)
#pragma unroll
            for (int r = 0; r < 4; ++r) {
                sacc[kvb][r] = exp2f(sacc[kvb][r] - m_s);
                ps += sacc[kvb][r];
            }
        l_s += ps;                                // per-lane partial; reduced at epilogue
        // ---- P -> B-frags, fully lane-local (sigma-order): pb[ks] words =
        //      {pk(p[2ks][0,1]), pk(p[2ks][2,3]), pk(p[2ks+1][0,1]), pk(p[2ks+1][2,3])}
        union { bf16x8 v; uint32_t u[4]; } pb[2];
#pragma unroll
        for (int kvb = 0; kvb < 4; ++kvb) {
            uint32_t lo, hi;
            asm("v_cvt_pk_bf16_f32 %0, %1, %2" : "=v"(lo) : "v"(sacc[kvb][0]), "v"(sacc[kvb][1]));
            asm("v_cvt_pk_bf16_f32 %0, %1, %2" : "=v"(hi) : "v"(sacc[kvb][2]), "v"(sacc[kvb][3]));
            pb[kvb >> 1].u[(kvb & 1) * 2]     = lo;
            pb[kvb >> 1].u[(kvb & 1) * 2 + 1] = hi;
        }
        // ---- PV (swapped): O^T[d][q] += V^T-frag x P-frag, contraction in sigma-order
#pragma unroll
        for (int ks = 0; ks < 2; ++ks)
#pragma unroll
            for (int nb = 0; nb < 8; ++nb) {
                bf16x8 bv = *(const bf16x8*)&VTs[(nb * 16 + ql) * 64 +
                                                 (((ks * 4 + kg) ^ (ql & 7)) * 8)];
                acc_o[nb] = MFMA(bv, pb[ks].v, acc_o[nb]);
            }
        __builtin_amdgcn_s_barrier();
        // stage next V (single buffer: all PV reads done) and next-next K
        if (it + 1 <= qt) {
            STAGE_V(it + 1);
            if (it + 2 <= qt) STAGE_K(cur, it + 2);
        }
    }

    // ---- epilogue: reduce l across the row's 4 kg-lanes, normalize, write O
    float lv = l_s;
    lv += __shfl_xor(lv, 16);
    lv += __shfl_xor(lv, 32);
    const float inv = 1.0f / lv;
    const size_t orow = (size_t)(qw + ql) * HID + h * DH;
#pragma unroll
    for (int nb = 0; nb < 8; ++nb) {
        uint32_t a, b;
        const float o0 = acc_o[nb][0] * inv, o1 = acc_o[nb][1] * inv;
        const float o2 = acc_o[nb][2] * inv, o3 = acc_o[nb][3] * inv;
        asm("v_cvt_pk_bf16_f32 %0, %1, %2" : "=v"(a) : "v"(o0), "v"(o1));
        asm("v_cvt_pk_bf16_f32 %0, %1, %2" : "=v"(b) : "v"(o2), "v"(o3));
        *(uint2*)&O[orow + nb * 16 + kg * 4] = make_uint2(a, b);
    }
}

// ---------------- launch ----------------
extern "C" void kernel_launch(void* const* d_in, const int* in_sizes, int n_in,
                              void* d_out, int out_size, void* d_ws, size_t ws_size,
                              hipStream_t stream) {
    const float* x    = (const float*)d_in[0];
    const float* cosb = (const float*)d_in[1];
    const float* sinb = (const float*)d_in[2];
    const float* wq   = (const float*)d_in[3];
    const float* bq   = (const float*)d_in[4];
    const float* wk   = (const float*)d_in[5];
    const float* bk   = (const float*)d_in[6];
    const float* wv   = (const float*)d_in[7];
    const float* bv   = (const float*)d_in[8];
    const float* wo   = (const float*)d_in[9];
    float* out = (float*)d_out;

    char* ws = (char*)d_ws;
    u16*   x_bf    = (u16*)(ws);
    u16*   Qb      = (u16*)(ws);                       // alias: x_bf dead after GEMM1
    u16*   wqkv_bf = (u16*)(ws + 16777216);
    u16*   wo_bf   = (u16*)(ws + 27262976);
    float* bias    = (float*)(ws + 35651584);
    u16*   qkv     = (u16*)(ws + 35667968);
    u16*   Ob      = (u16*)(ws + 35667968);            // alias: qkv dead after rope
    u16*   Kb      = (u16*)(ws + 56639488);
    u16*   VTb     = (u16*)(ws + 58736640);

    k_cvt_all<<<17408, 256, 0, stream>>>((const float4*)x, (const float4*)wq,
                                         (const float4*)wk, (const float4*)wv,
                                         (const float4*)wo, x_bf, wqkv_bf, wo_bf);
    k_bias<<<10, 256, 0, stream>>>(bq, bk, bv, bias);

    // QKV projection (+bias): [4096,2048] @ [2560,2048]^T -> bf16 [4096,2560]
    k_gemm_bt<1><<<dim3(32, 20), 256, 0, stream>>>(x_bf, wqkv_bf, bias, qkv, 4096, 2560, 2048);
    // RoPE + attention layouts (Q pre-scaled; K/V pre-swizzled, V tau-permuted)
    k_rope<<<dim3(10, 4096), 256, 0, stream>>>(qkv, cosb, sinb, Qb, Kb, VTb);
    // flash attention: 1024 single-tile blocks, heavy-first, 3 blocks/CU
    k_attn<<<1024, 256, 0, stream>>>(Qb, Kb, VTb, Ob);
    // output projection: [4096,2048] @ [2048,2048]^T -> fp32 d_out
    k_gemm_bt<0><<<dim3(32, 16), 256, 0, stream>>>(Ob, wo_bf, nullptr, out, 4096, 2048, 2048);
}